// Round 1
// baseline (298.733 us; speedup 1.0000x reference)
//
#include <hip/hip_runtime.h>
#include <hip/hip_bf16.h>

// SelfAttention fp32 I/O, bf16 MFMA internals.
// R6: attn VALU diet + occupancy. Keeps R5's 32x32 S^T/O^T engine and LDS-staged
// K/V, but: (1) P never touches LDS — packed with v_cvt_pk_bf16_f32 and
// redistributed across half-waves with v_permlane32_swap_b32 (T12); (2) softmax
// scale folded into the exp FMA (raw-unit max tracking); (3) defer-rescale (T13):
// O-rescale skipped unless the tile max grows past a threshold; (4) grid 16x64,
// one 128-row q-block per block, heavy blocks first (LPT) -> 4 blocks/CU instead
// of 2. Epilogue transpose bounces through the dead K/V LDS (block LDS 16 KB).

typedef unsigned short ushort_t;
typedef __attribute__((ext_vector_type(8))) short short8;
typedef __attribute__((ext_vector_type(4))) float floatx4;
typedef __attribute__((ext_vector_type(16))) float floatx16;
typedef __attribute__((ext_vector_type(2))) unsigned uintx2;

#define NH   16
#define SEQ  2048
#define EMB  1024
#define HDIM 64

#define MFMA32(a, b, c) __builtin_amdgcn_mfma_f32_32x32x16_bf16(a, b, c, 0, 0, 0)

__device__ __forceinline__ ushort_t f2bf(float f) {
    union { float f; unsigned u; } v; v.f = f;
    unsigned r = (v.u + 0x7fffu + ((v.u >> 16) & 1u)) >> 16;  // RNE
    return (ushort_t)r;
}

// 2x f32 -> packed bf16 (RNE), single VALU op
__device__ __forceinline__ unsigned cvtpk(float lo, float hi) {
    unsigned r;
    asm("v_cvt_pk_bf16_f32 %0, %1, %2" : "=v"(r) : "v"(lo), "v"(hi));
    return r;
}

// new_a = {a.lo, b.lo}, new_b = {a.hi, b.hi}  (cross half-wave exchange)
__device__ __forceinline__ uintx2 pl32(unsigned a, unsigned b) {
    return __builtin_amdgcn_permlane32_swap(a, b, false, false);
}

__device__ __forceinline__ short8 mk8(unsigned a, unsigned b, unsigned c, unsigned d) {
    union { unsigned w[4]; short8 s; } t;
    t.w[0] = a; t.w[1] = b; t.w[2] = c; t.w[3] = d;
    return t.s;
}

#if defined(__has_builtin) && __has_builtin(__builtin_amdgcn_global_load_lds)
#define HAS_GLL 1
__device__ __forceinline__ void gload16(const ushort_t* g, ushort_t* l) {
    __builtin_amdgcn_global_load_lds((const __attribute__((address_space(1))) void*)g,
                                     (__attribute__((address_space(3))) void*)l, 16, 0, 0);
}
#else
#define HAS_GLL 0
#endif

// ---------------- fp32 -> bf16 cast (8 elems/thread) ----------------
__global__ __launch_bounds__(256) void cast_k(const float* __restrict__ in,
                                              ushort_t* __restrict__ out) {
    int i = blockIdx.x * 256 + threadIdx.x;
    float4 v0 = ((const float4*)in)[i * 2];
    float4 v1 = ((const float4*)in)[i * 2 + 1];
    short8 t;
    t[0] = (short)f2bf(v0.x); t[1] = (short)f2bf(v0.y);
    t[2] = (short)f2bf(v0.z); t[3] = (short)f2bf(v0.w);
    t[4] = (short)f2bf(v1.x); t[5] = (short)f2bf(v1.y);
    t[6] = (short)f2bf(v1.z); t[7] = (short)f2bf(v1.w);
    ((short8*)out)[i] = t;
}

// ---------------- transpose + fp32->bf16 cast ----------------
__global__ void transpose_cast_k(const float* __restrict__ in, ushort_t* __restrict__ out,
                                 int R, int Cc) {
    __shared__ ushort_t tile[32][33];
    int x  = blockIdx.x * 32 + threadIdx.x;
    int y0 = blockIdx.y * 32;
#pragma unroll
    for (int i = 0; i < 32; i += 8)
        tile[threadIdx.y + i][threadIdx.x] = f2bf(in[(size_t)(y0 + threadIdx.y + i) * Cc + x]);
    __syncthreads();
    int xo = blockIdx.y * 32 + threadIdx.x;
    int yo = blockIdx.x * 32;
#pragma unroll
    for (int i = 0; i < 32; i += 8)
        out[(size_t)(yo + threadIdx.y + i) * R + xo] = tile[threadIdx.x][threadIdx.y + i];
}

// ---------------- batched V transpose: Vb[bh][c][d] -> Vt[bh][d][c] ----------------
__global__ void transpose_v_k(const ushort_t* __restrict__ in, ushort_t* __restrict__ out) {
    __shared__ ushort_t tile[32][33];
    int bh = blockIdx.z;
    int c0 = blockIdx.x * 32, d0 = blockIdx.y * 32;
#pragma unroll
    for (int i = 0; i < 32; i += 8)
        tile[threadIdx.y + i][threadIdx.x] =
            in[((size_t)bh * SEQ + c0 + threadIdx.y + i) * HDIM + d0 + threadIdx.x];
    __syncthreads();
#pragma unroll
    for (int i = 0; i < 32; i += 8)
        out[((size_t)bh * HDIM + d0 + threadIdx.y + i) * SEQ + c0 + threadIdx.x] =
            tile[threadIdx.x][threadIdx.y + i];
}

// ---------------- GEMM: C[m][n] = sum_k A[m][k] * Bt[n][k] (both bf16) ----------------
template<int EPI>
__global__ __launch_bounds__(256) void gemm_bt(const ushort_t* __restrict__ A,
                                               const ushort_t* __restrict__ Bt,
                                               void* __restrict__ O0v,
                                               ushort_t* __restrict__ O1,
                                               ushort_t* __restrict__ O2,
                                               int M, int N, int K) {
    __shared__ __align__(16) ushort_t As[128 * 64];
    __shared__ __align__(16) ushort_t Bs[128 * 64];
    const int tid  = threadIdx.x;
    const int wv   = tid >> 6, lane = tid & 63, quad = lane >> 4, l15 = lane & 15;
    const int wm   = wv >> 1, wn = wv & 1;
    const int bm   = blockIdx.x, bn = blockIdx.y;
    const int lrow = lane >> 3;
    const int kg   = (lane & 7) ^ (lrow & 7);
    const int sw   = l15 & 7;

    floatx4 acc[4][4];
#pragma unroll
    for (int i = 0; i < 4; i++)
#pragma unroll
        for (int j = 0; j < 4; j++) acc[i][j] = (floatx4){0.f, 0.f, 0.f, 0.f};

    for (int kt = 0; kt < K; kt += 64) {
#pragma unroll
        for (int it = 0; it < 4; it++) {
            int r0 = it * 32 + wv * 8;
            const ushort_t* ga = &A [(size_t)(bm * 128 + r0 + lrow) * K + kt + kg * 8];
            const ushort_t* gb = &Bt[(size_t)(bn * 128 + r0 + lrow) * K + kt + kg * 8];
#if HAS_GLL
            gload16(ga, &As[r0 * 64]);
            gload16(gb, &Bs[r0 * 64]);
#else
            *(uint4*)&As[(r0 + lrow) * 64 + (lane & 7) * 8] = *(const uint4*)ga;
            *(uint4*)&Bs[(r0 + lrow) * 64 + (lane & 7) * 8] = *(const uint4*)gb;
#endif
        }
        __syncthreads();
#pragma unroll
        for (int ks = 0; ks < 2; ks++) {
            short8 af[4], bf[4];
#pragma unroll
            for (int i = 0; i < 4; i++)
                af[i] = *(const short8*)&As[(wm * 64 + i * 16 + l15) * 64 + (((ks * 4 + quad) ^ sw) * 8)];
#pragma unroll
            for (int j = 0; j < 4; j++)
                bf[j] = *(const short8*)&Bs[(wn * 64 + j * 16 + l15) * 64 + (((ks * 4 + quad) ^ sw) * 8)];
#pragma unroll
            for (int i = 0; i < 4; i++)
#pragma unroll
                for (int j = 0; j < 4; j++)
                    acc[i][j] = __builtin_amdgcn_mfma_f32_16x16x32_bf16(af[i], bf[j], acc[i][j], 0, 0, 0);
        }
        __syncthreads();
    }

#pragma unroll
    for (int i = 0; i < 4; i++)
#pragma unroll
        for (int j = 0; j < 4; j++)
#pragma unroll
            for (int r = 0; r < 4; r++) {
                int row = bm * 128 + wm * 64 + i * 16 + quad * 4 + r;   // C/D: row=quad*4+reg
                int col = bn * 128 + wn * 64 + j * 16 + l15;
                if (EPI == 0) {
                    ((float*)O0v)[(size_t)row * N + col] = acc[i][j][r];
                } else {
                    ushort_t v = f2bf(acc[i][j][r]);
                    int b = row >> 11, c = row & 2047;
                    int which = col >> 10, nn = col & 1023;
                    int hh = nn >> 6, d = nn & 63;
                    ushort_t* dst = (which == 0) ? (ushort_t*)O0v : (which == 1) ? O1 : O2;
                    dst[((size_t)(b * NH + hh) * SEQ + c) * HDIM + d] = v;
                }
            }
}

// ---------------- flash attention v4: in-register P, LDS-staged K/V, LPT grid ----------
// grid (16 z, 64 bh); 256 thr = 4 waves; qb = 15 - z so heavy blocks dispatch first.
// Per j-tile, K[64][64] and V^T[64][64] staged once to LDS (global_load_lds, XOR
// swizzle) and shared by 4 waves. Softmax state per lane (q = lane&31); P is packed
// in-register (cvt_pk_bf16) and exchanged across half-waves with permlane32_swap.
__global__ __launch_bounds__(256) void attn3_k(const ushort_t* __restrict__ Qg,
                                               const ushort_t* __restrict__ Kg,
                                               const ushort_t* __restrict__ Vtg,
                                               ushort_t* __restrict__ Y) {
    __shared__ __align__(16) ushort_t SM[2 * 64 * 64];   // Ks | Vs, 16 KB total
    ushort_t* Ks = SM;
    ushort_t* Vs = SM + 64 * 64;
    const int tid  = threadIdx.x;
    const int wv   = tid >> 6, lane = tid & 63;
    const int l31  = lane & 31, hf = lane >> 5;
    const int bh   = blockIdx.y;
    const int qb   = 15 - blockIdx.x;           // LPT: heaviest q-blocks first
    const int qs7  = l31 & 7;
    const int lrow = lane >> 3;                 // staging row-in-chunk
    const int kgs  = (lane & 7) ^ (lrow & 7);   // staging global chunk (XOR swizzle)
    const int b = bh >> 4, hh = bh & 15;
    const float c2 = 0.18033688011112042f;      // 0.125 * log2(e)

    const int qrow0 = qb * 128 + wv * 32;
    const int q_abs = qrow0 + l31;
    const int jmax_w = 2 * qb + (wv >> 1);      // waves 2,3 reach one tile further
    const int jmax_b = 2 * qb + 1;

    // Q B-frags (n=q=l31, k = ks*16 + hf*8 + j)
    short8 qf[4];
    {
        const ushort_t* qp = Qg + ((size_t)bh * SEQ + q_abs) * HDIM + hf * 8;
#pragma unroll
        for (int ks = 0; ks < 4; ks++) qf[ks] = *(const short8*)(qp + ks * 16);
    }

    floatx16 o0, o1;
#pragma unroll
    for (int r = 0; r < 16; r++) { o0[r] = 0.f; o1[r] = 0.f; }
    float m_i = -1e30f, l_i = 0.f;              // m_i tracked in RAW score units

    for (int j = 0; j <= jmax_b; j++) {
        // ---- stage K tile + V^T tile (16 KB) cooperatively ----
#pragma unroll
        for (int it = 0; it < 2; it++) {
            int r0 = it * 32 + wv * 8;
            const ushort_t* gk = &Kg [((size_t)bh * SEQ  + j * 64 + r0 + lrow) * HDIM + kgs * 8];
            const ushort_t* gv = &Vtg[((size_t)bh * HDIM + r0 + lrow) * SEQ + j * 64 + kgs * 8];
#if HAS_GLL
            gload16(gk, &Ks[r0 * 64]);
            gload16(gv, &Vs[r0 * 64]);
#else
            *(uint4*)&Ks[(r0 + lrow) * 64 + (lane & 7) * 8] = *(const uint4*)gk;
            *(uint4*)&Vs[(r0 + lrow) * 64 + (lane & 7) * 8] = *(const uint4*)gv;
#endif
        }
        __syncthreads();

        if (j <= jmax_w) {
            // ---- S^T = K Q^T (raw, unscaled) ----
            floatx16 s0, s1;
#pragma unroll
            for (int r = 0; r < 16; r++) { s0[r] = 0.f; s1[r] = 0.f; }
#pragma unroll
            for (int ks = 0; ks < 4; ks++) {
                int slot = ((hf + 2 * ks) ^ qs7) * 8;
                short8 k0 = *(const short8*)&Ks[l31 * 64 + slot];
                short8 k1 = *(const short8*)&Ks[(32 + l31) * 64 + slot];
                s0 = MFMA32(k0, qf[ks], s0);
                s1 = MFMA32(k1, qf[ks], s1);
            }

            // ---- causal mask on own boundary tile only ----
            if (j == jmax_w) {
                const int kb0 = j * 64 + 4 * hf;
#pragma unroll
                for (int r = 0; r < 16; r++) {
                    int key = kb0 + (r & 3) + 8 * (r >> 2);
                    if (key > q_abs)      s0[r] = -1e30f;
                    if (key + 32 > q_abs) s1[r] = -1e30f;
                }
            }

            // ---- tile max (raw units), shared with partner half-wave ----
            float mx = -1e30f;
#pragma unroll
            for (int r = 0; r < 16; r++) mx = fmaxf(mx, fmaxf(s0[r], s1[r]));
            mx = fmaxf(mx, __shfl_xor(mx, 32));

            // ---- defer-rescale (T13): only rescale when max grows materially ----
            if (__any(mx > m_i + 20.0f)) {
                float m_new = fmaxf(m_i, mx);
                float alpha = __builtin_amdgcn_exp2f((m_i - m_new) * c2);
                m_i = m_new;
                l_i *= alpha;
#pragma unroll
                for (int r = 0; r < 16; r++) { o0[r] *= alpha; o1[r] *= alpha; }
            }

            // ---- P = 2^(s*c2 - m*c2)  (scale folded into one FMA) ----
            const float nem = -m_i * c2;
            float rs0 = 0.f, rs1 = 0.f;
#pragma unroll
            for (int r = 0; r < 16; r++) {
                s0[r] = __builtin_amdgcn_exp2f(__builtin_fmaf(s0[r], c2, nem));
                s1[r] = __builtin_amdgcn_exp2f(__builtin_fmaf(s1[r], c2, nem));
                rs0 += s0[r]; rs1 += s1[r];
            }
            float rs = rs0 + rs1;
            rs += __shfl_xor(rs, 32);
            l_i += rs;

            // ---- pack P to bf16 words in-register (T12) ----
            // quad g of s0 = keys 8g + 4hf + {0..3}; word i of quad g = u[2g+i]
            unsigned u0[8], u1[8];
#pragma unroll
            for (int g = 0; g < 4; g++) {
                u0[2 * g]     = cvtpk(s0[4 * g],     s0[4 * g + 1]);
                u0[2 * g + 1] = cvtpk(s0[4 * g + 2], s0[4 * g + 3]);
                u1[2 * g]     = cvtpk(s1[4 * g],     s1[4 * g + 1]);
                u1[2 * g + 1] = cvtpk(s1[4 * g + 2], s1[4 * g + 3]);
            }
            // permlane32_swap pairs matching words of adjacent quads:
            //   new_a = {a.lo, b.lo} -> B-frag word for keys base+8hf+{..}   (low  k-half)
            //   new_b = {a.hi, b.hi} -> B-frag word for keys base+8hf+4+{..} (high k-half)
            unsigned pw[16];
#pragma unroll
            for (int t = 0; t < 2; t++) {
                const unsigned* u = t ? u1 : u0;
#pragma unroll
                for (int p = 0; p < 2; p++) {
#pragma unroll
                    for (int i = 0; i < 2; i++) {
                        uintx2 r = pl32(u[4 * p + i], u[4 * p + 2 + i]);
                        pw[8 * t + 4 * p + i]     = r[0];
                        pw[8 * t + 4 * p + 2 + i] = r[1];
                    }
                }
            }

            // ---- O^T += V^T P^T ----
#pragma unroll
            for (int ks = 0; ks < 4; ks++) {
                int slot = ((hf + 2 * ks) ^ qs7) * 8;
                short8 v0 = *(const short8*)&Vs[l31 * 64 + slot];
                short8 v1 = *(const short8*)&Vs[(32 + l31) * 64 + slot];
                short8 pf = mk8(pw[4 * ks], pw[4 * ks + 1], pw[4 * ks + 2], pw[4 * ks + 3]);
                o0 = MFMA32(v0, pf, o0);
                o1 = MFMA32(v1, pf, o1);
            }
        }
        __syncthreads();
    }

    // ---- epilogue: /l, transpose via per-wave chunk of the (dead) K/V LDS ----
    ushort_t* Ew = SM + wv * 2048;              // 32x64 bf16 per wave
    float inv = 1.0f / l_i;
#pragma unroll
    for (int g = 0; g < 4; g++) {
        uint2 w0, w1;
        w0.x = cvtpk(o0[g * 4] * inv,     o0[g * 4 + 1] * inv);
        w0.y = cvtpk(o0[g * 4 + 2] * inv, o0[g * 4 + 3] * inv);
        w1.x = cvtpk(o1[g * 4] * inv,     o1[g * 4 + 1] * inv);
        w1.y = cvtpk(o1[g * 4 + 2] * inv, o1[g * 4 + 3] * inv);
        *(uint2*)&Ew[l31 * 64 + ((g       ^ qs7) * 8) + 4 * hf] = w0;   // d 8g+4hf+{0..3}
        *(uint2*)&Ew[l31 * 64 + (((4 + g) ^ qs7) * 8) + 4 * hf] = w1;   // d+32
    }
    const int dg = lane & 7;
#pragma unroll
    for (int sb = 0; sb < 4; sb++) {
        int ql = sb * 8 + (lane >> 3);
        uint4 v = *(const uint4*)&Ew[ql * 64 + ((dg ^ (ql & 7)) * 8)];
        *(uint4*)&Y[((size_t)(b * SEQ + qrow0 + ql)) * EMB + hh * HDIM + dg * 8] = v;
    }
}

// ---------------- launch ----------------
extern "C" void kernel_launch(void* const* d_in, const int* in_sizes, int n_in,
                              void* d_out, int out_size, void* d_ws, size_t ws_size,
                              hipStream_t stream) {
    const float* x      = (const float*)d_in[0];   // [8192][1024] fp32
    const float* W_attn = (const float*)d_in[1];   // [1024][3072] fp32
    const float* W_proj = (const float*)d_in[2];   // [1024][1024] fp32

    char* ws = (char*)d_ws;
    ushort_t* Wt_attn = (ushort_t*)(ws);                 // [3072][1024] bf16  6.3 MB
    ushort_t* Wt_proj = (ushort_t*)(ws + 6291456);       // [1024][1024] bf16  2.1 MB
    ushort_t* Xb      = (ushort_t*)(ws + 8388608);       // [8192][1024] bf16 16.8 MB
    ushort_t* Vt      = Xb;                              // alias: Xb dead after QKV gemm
    ushort_t* Qb      = (ushort_t*)(ws + 25165824);      // [64][2048][64]
    ushort_t* Kb      = (ushort_t*)(ws + 41943040);      // [64][2048][64]
    ushort_t* Vb      = (ushort_t*)(ws + 58720256);      // [64][2048][64]
    ushort_t* Yb      = Vb;                              // alias: Vb dead after transpose_v
    // total ws use: 75,497,472 B

    cast_k<<<4096, 256, 0, stream>>>(x, Xb);
    transpose_cast_k<<<dim3(3072 / 32, 1024 / 32), dim3(32, 8), 0, stream>>>(W_attn, Wt_attn, 1024, 3072);
    transpose_cast_k<<<dim3(1024 / 32, 1024 / 32), dim3(32, 8), 0, stream>>>(W_proj, Wt_proj, 1024, 1024);
    gemm_bt<1><<<dim3(8192 / 128, 3072 / 128), 256, 0, stream>>>(Xb, Wt_attn, Qb, Kb, Vb, 8192, 3072, 1024);
    transpose_v_k<<<dim3(SEQ / 32, HDIM / 32, 64), dim3(32, 8), 0, stream>>>(Vb, Vt);
    attn3_k<<<dim3(16, 64), 256, 0, stream>>>(Qb, Kb, Vt, Yb);
    gemm_bt<0><<<dim3(8192 / 128, 1024 / 128), 256, 0, stream>>>(Yb, Wt_proj, d_out,
                                                                 nullptr, nullptr, 8192, 1024, 1024);
}

// Round 2
// 253.789 us; speedup vs baseline: 1.1771x; 1.1771x over previous
//
#include <hip/hip_runtime.h>
#include <hip/hip_bf16.h>

// SelfAttention fp32 I/O, bf16 MFMA internals.
// R7: revert R6's grid split (it drained occupancy 19->11: all 1024 unequal
// blocks co-resident from t=0, no backfill, long tail). Back to the paired
// {z, 15-z} grid (8x64) where every block = exactly 36 staged j-tiles. Keeps
// R6's verified VALU diet (in-register P via v_cvt_pk_bf16_f32 + permlane32_swap,
// scale folded into exp FMA, defer-rescale). NEW: T3 minimum 2-phase pipeline —
// double-buffered K/V (2x16 KB), next-tile global_load_lds issued BEFORE current
// tile's compute, raw s_barrier + manual s_waitcnt vmcnt(0) after compute so the
// staging loads stay in flight under the MFMA+softmax phase. T5 setprio around
// MFMA clusters.

typedef unsigned short ushort_t;
typedef __attribute__((ext_vector_type(8))) short short8;
typedef __attribute__((ext_vector_type(4))) float floatx4;
typedef __attribute__((ext_vector_type(16))) float floatx16;
typedef __attribute__((ext_vector_type(2))) unsigned uintx2;

#define NH   16
#define SEQ  2048
#define EMB  1024
#define HDIM 64

#define MFMA32(a, b, c) __builtin_amdgcn_mfma_f32_32x32x16_bf16(a, b, c, 0, 0, 0)

__device__ __forceinline__ ushort_t f2bf(float f) {
    union { float f; unsigned u; } v; v.f = f;
    unsigned r = (v.u + 0x7fffu + ((v.u >> 16) & 1u)) >> 16;  // RNE
    return (ushort_t)r;
}

// 2x f32 -> packed bf16 (RNE), single VALU op
__device__ __forceinline__ unsigned cvtpk(float lo, float hi) {
    unsigned r;
    asm("v_cvt_pk_bf16_f32 %0, %1, %2" : "=v"(r) : "v"(lo), "v"(hi));
    return r;
}

// new_a = {a.lo, b.lo}, new_b = {a.hi, b.hi}  (cross half-wave exchange)
__device__ __forceinline__ uintx2 pl32(unsigned a, unsigned b) {
    return __builtin_amdgcn_permlane32_swap(a, b, false, false);
}

__device__ __forceinline__ short8 mk8(unsigned a, unsigned b, unsigned c, unsigned d) {
    union { unsigned w[4]; short8 s; } t;
    t.w[0] = a; t.w[1] = b; t.w[2] = c; t.w[3] = d;
    return t.s;
}

#if defined(__has_builtin) && __has_builtin(__builtin_amdgcn_global_load_lds)
#define HAS_GLL 1
__device__ __forceinline__ void gload16(const ushort_t* g, ushort_t* l) {
    __builtin_amdgcn_global_load_lds((const __attribute__((address_space(1))) void*)g,
                                     (__attribute__((address_space(3))) void*)l, 16, 0, 0);
}
#else
#define HAS_GLL 0
#endif

// ---------------- fp32 -> bf16 cast (8 elems/thread) ----------------
__global__ __launch_bounds__(256) void cast_k(const float* __restrict__ in,
                                              ushort_t* __restrict__ out) {
    int i = blockIdx.x * 256 + threadIdx.x;
    float4 v0 = ((const float4*)in)[i * 2];
    float4 v1 = ((const float4*)in)[i * 2 + 1];
    short8 t;
    t[0] = (short)f2bf(v0.x); t[1] = (short)f2bf(v0.y);
    t[2] = (short)f2bf(v0.z); t[3] = (short)f2bf(v0.w);
    t[4] = (short)f2bf(v1.x); t[5] = (short)f2bf(v1.y);
    t[6] = (short)f2bf(v1.z); t[7] = (short)f2bf(v1.w);
    ((short8*)out)[i] = t;
}

// ---------------- transpose + fp32->bf16 cast ----------------
__global__ void transpose_cast_k(const float* __restrict__ in, ushort_t* __restrict__ out,
                                 int R, int Cc) {
    __shared__ ushort_t tile[32][33];
    int x  = blockIdx.x * 32 + threadIdx.x;
    int y0 = blockIdx.y * 32;
#pragma unroll
    for (int i = 0; i < 32; i += 8)
        tile[threadIdx.y + i][threadIdx.x] = f2bf(in[(size_t)(y0 + threadIdx.y + i) * Cc + x]);
    __syncthreads();
    int xo = blockIdx.y * 32 + threadIdx.x;
    int yo = blockIdx.x * 32;
#pragma unroll
    for (int i = 0; i < 32; i += 8)
        out[(size_t)(yo + threadIdx.y + i) * R + xo] = tile[threadIdx.x][threadIdx.y + i];
}

// ---------------- batched V transpose: Vb[bh][c][d] -> Vt[bh][d][c] ----------------
__global__ void transpose_v_k(const ushort_t* __restrict__ in, ushort_t* __restrict__ out) {
    __shared__ ushort_t tile[32][33];
    int bh = blockIdx.z;
    int c0 = blockIdx.x * 32, d0 = blockIdx.y * 32;
#pragma unroll
    for (int i = 0; i < 32; i += 8)
        tile[threadIdx.y + i][threadIdx.x] =
            in[((size_t)bh * SEQ + c0 + threadIdx.y + i) * HDIM + d0 + threadIdx.x];
    __syncthreads();
#pragma unroll
    for (int i = 0; i < 32; i += 8)
        out[((size_t)bh * HDIM + d0 + threadIdx.y + i) * SEQ + c0 + threadIdx.x] =
            tile[threadIdx.x][threadIdx.y + i];
}

// ---------------- GEMM: C[m][n] = sum_k A[m][k] * Bt[n][k] (both bf16) ----------------
template<int EPI>
__global__ __launch_bounds__(256) void gemm_bt(const ushort_t* __restrict__ A,
                                               const ushort_t* __restrict__ Bt,
                                               void* __restrict__ O0v,
                                               ushort_t* __restrict__ O1,
                                               ushort_t* __restrict__ O2,
                                               int M, int N, int K) {
    __shared__ __align__(16) ushort_t As[128 * 64];
    __shared__ __align__(16) ushort_t Bs[128 * 64];
    const int tid  = threadIdx.x;
    const int wv   = tid >> 6, lane = tid & 63, quad = lane >> 4, l15 = lane & 15;
    const int wm   = wv >> 1, wn = wv & 1;
    const int bm   = blockIdx.x, bn = blockIdx.y;
    const int lrow = lane >> 3;
    const int kg   = (lane & 7) ^ (lrow & 7);
    const int sw   = l15 & 7;

    floatx4 acc[4][4];
#pragma unroll
    for (int i = 0; i < 4; i++)
#pragma unroll
        for (int j = 0; j < 4; j++) acc[i][j] = (floatx4){0.f, 0.f, 0.f, 0.f};

    for (int kt = 0; kt < K; kt += 64) {
#pragma unroll
        for (int it = 0; it < 4; it++) {
            int r0 = it * 32 + wv * 8;
            const ushort_t* ga = &A [(size_t)(bm * 128 + r0 + lrow) * K + kt + kg * 8];
            const ushort_t* gb = &Bt[(size_t)(bn * 128 + r0 + lrow) * K + kt + kg * 8];
#if HAS_GLL
            gload16(ga, &As[r0 * 64]);
            gload16(gb, &Bs[r0 * 64]);
#else
            *(uint4*)&As[(r0 + lrow) * 64 + (lane & 7) * 8] = *(const uint4*)ga;
            *(uint4*)&Bs[(r0 + lrow) * 64 + (lane & 7) * 8] = *(const uint4*)gb;
#endif
        }
        __syncthreads();
#pragma unroll
        for (int ks = 0; ks < 2; ks++) {
            short8 af[4], bf[4];
#pragma unroll
            for (int i = 0; i < 4; i++)
                af[i] = *(const short8*)&As[(wm * 64 + i * 16 + l15) * 64 + (((ks * 4 + quad) ^ sw) * 8)];
#pragma unroll
            for (int j = 0; j < 4; j++)
                bf[j] = *(const short8*)&Bs[(wn * 64 + j * 16 + l15) * 64 + (((ks * 4 + quad) ^ sw) * 8)];
#pragma unroll
            for (int i = 0; i < 4; i++)
#pragma unroll
                for (int j = 0; j < 4; j++)
                    acc[i][j] = __builtin_amdgcn_mfma_f32_16x16x32_bf16(af[i], bf[j], acc[i][j], 0, 0, 0);
        }
        __syncthreads();
    }

#pragma unroll
    for (int i = 0; i < 4; i++)
#pragma unroll
        for (int j = 0; j < 4; j++)
#pragma unroll
            for (int r = 0; r < 4; r++) {
                int row = bm * 128 + wm * 64 + i * 16 + quad * 4 + r;   // C/D: row=quad*4+reg
                int col = bn * 128 + wn * 64 + j * 16 + l15;
                if (EPI == 0) {
                    ((float*)O0v)[(size_t)row * N + col] = acc[i][j][r];
                } else {
                    ushort_t v = f2bf(acc[i][j][r]);
                    int b = row >> 11, c = row & 2047;
                    int which = col >> 10, nn = col & 1023;
                    int hh = nn >> 6, d = nn & 63;
                    ushort_t* dst = (which == 0) ? (ushort_t*)O0v : (which == 1) ? O1 : O2;
                    dst[((size_t)(b * NH + hh) * SEQ + c) * HDIM + d] = v;
                }
            }
}

// ---------------- flash attention v5: paired qb, dbuf K/V pipeline, in-reg P ----------
// grid (8 z, 64 bh); 256 thr = 4 waves. Block processes qb = z then qb = 15-z
// (exactly 36 staged j-tiles -> perfect balance, no tail). Per j-tile, K[64][64]
// and V^T[64][64] staged to the ALTERNATE LDS set while the current set is
// consumed; raw s_barrier + one manual vmcnt(0) per tile (after compute) keeps
// the 4 staging loads in flight under the MFMA+softmax phase (T3 2-phase).
// P stays in registers (cvt_pk_bf16 + permlane32_swap, T12); defer-rescale (T13).
__global__ __launch_bounds__(256) void attn3_k(const ushort_t* __restrict__ Qg,
                                               const ushort_t* __restrict__ Kg,
                                               const ushort_t* __restrict__ Vtg,
                                               ushort_t* __restrict__ Y) {
    __shared__ __align__(16) ushort_t SM[4 * 64 * 64];   // {K0,V0,K1,V1}, 32 KB
    const int tid  = threadIdx.x;
    const int wv   = tid >> 6, lane = tid & 63;
    const int l31  = lane & 31, hf = lane >> 5;
    const int z    = blockIdx.x, bh = blockIdx.y;
    const int qs7  = l31 & 7;
    const int lrow = lane >> 3;                 // staging row-in-chunk
    const int kgs  = (lane & 7) ^ (lrow & 7);   // staging global chunk (XOR swizzle)
    const int b = bh >> 4, hh = bh & 15;
    const float c2 = 0.18033688011112042f;      // 0.125 * log2(e)

    for (int pp = 0; pp < 2; pp++) {
        const int qb = pp ? (15 - z) : z;
        const int qrow0 = qb * 128 + wv * 32;
        const int q_abs = qrow0 + l31;
        const int jmax_w = 2 * qb + (wv >> 1);  // waves 2,3 reach one tile further
        const int jmax_b = 2 * qb + 1;

        // Q B-frags (n=q=l31, k = ks*16 + hf*8 + j)
        short8 qf[4];
        {
            const ushort_t* qp = Qg + ((size_t)bh * SEQ + q_abs) * HDIM + hf * 8;
#pragma unroll
            for (int ks = 0; ks < 4; ks++) qf[ks] = *(const short8*)(qp + ks * 16);
        }

        floatx16 o0, o1;
#pragma unroll
        for (int r = 0; r < 16; r++) { o0[r] = 0.f; o1[r] = 0.f; }
        float m_i = -1e30f, l_i = 0.f;          // m_i tracked in RAW score units

        // ---- prologue: stage tile j=0 into set 0 ----
        {
            ushort_t* Kn = SM;
            ushort_t* Vn = SM + 4096;
#pragma unroll
            for (int it = 0; it < 2; it++) {
                int r0 = it * 32 + wv * 8;
                const ushort_t* gk = &Kg [((size_t)bh * SEQ  + r0 + lrow) * HDIM + kgs * 8];
                const ushort_t* gv = &Vtg[((size_t)bh * HDIM + r0 + lrow) * SEQ + kgs * 8];
#if HAS_GLL
                gload16(gk, &Kn[r0 * 64]);
                gload16(gv, &Vn[r0 * 64]);
#else
                *(uint4*)&Kn[(r0 + lrow) * 64 + (lane & 7) * 8] = *(const uint4*)gk;
                *(uint4*)&Vn[(r0 + lrow) * 64 + (lane & 7) * 8] = *(const uint4*)gv;
#endif
            }
        }
        asm volatile("s_waitcnt vmcnt(0)" ::: "memory");
        __builtin_amdgcn_s_barrier();

        int cur = 0;
        for (int j = 0; j <= jmax_b; j++) {
            ushort_t* Ks = SM + cur * 8192;
            ushort_t* Vs = Ks + 4096;

            // ---- issue next-tile staging into the alternate set (overlaps compute) ----
            if (j < jmax_b) {
                ushort_t* Kn = SM + (cur ^ 1) * 8192;
                ushort_t* Vn = Kn + 4096;
#pragma unroll
                for (int it = 0; it < 2; it++) {
                    int r0 = it * 32 + wv * 8;
                    const ushort_t* gk = &Kg [((size_t)bh * SEQ  + (j + 1) * 64 + r0 + lrow) * HDIM + kgs * 8];
                    const ushort_t* gv = &Vtg[((size_t)bh * HDIM + r0 + lrow) * SEQ + (j + 1) * 64 + kgs * 8];
#if HAS_GLL
                    gload16(gk, &Kn[r0 * 64]);
                    gload16(gv, &Vn[r0 * 64]);
#else
                    *(uint4*)&Kn[(r0 + lrow) * 64 + (lane & 7) * 8] = *(const uint4*)gk;
                    *(uint4*)&Vn[(r0 + lrow) * 64 + (lane & 7) * 8] = *(const uint4*)gv;
#endif
                }
            }

            if (j <= jmax_w) {
                // ---- S^T = K Q^T (raw, unscaled) ----
                floatx16 s0, s1;
#pragma unroll
                for (int r = 0; r < 16; r++) { s0[r] = 0.f; s1[r] = 0.f; }
                __builtin_amdgcn_s_setprio(1);
#pragma unroll
                for (int ks = 0; ks < 4; ks++) {
                    int slot = ((hf + 2 * ks) ^ qs7) * 8;
                    short8 k0 = *(const short8*)&Ks[l31 * 64 + slot];
                    short8 k1 = *(const short8*)&Ks[(32 + l31) * 64 + slot];
                    s0 = MFMA32(k0, qf[ks], s0);
                    s1 = MFMA32(k1, qf[ks], s1);
                }
                __builtin_amdgcn_s_setprio(0);

                // ---- causal mask on own boundary tile only ----
                if (j == jmax_w) {
                    const int kb0 = j * 64 + 4 * hf;
#pragma unroll
                    for (int r = 0; r < 16; r++) {
                        int key = kb0 + (r & 3) + 8 * (r >> 2);
                        if (key > q_abs)      s0[r] = -1e30f;
                        if (key + 32 > q_abs) s1[r] = -1e30f;
                    }
                }

                // ---- tile max (raw units), shared with partner half-wave ----
                float mx = -1e30f;
#pragma unroll
                for (int r = 0; r < 16; r++) mx = fmaxf(mx, fmaxf(s0[r], s1[r]));
                mx = fmaxf(mx, __shfl_xor(mx, 32));

                // ---- defer-rescale (T13) ----
                if (__any(mx > m_i + 20.0f)) {
                    float m_new = fmaxf(m_i, mx);
                    float alpha = __builtin_amdgcn_exp2f((m_i - m_new) * c2);
                    m_i = m_new;
                    l_i *= alpha;
#pragma unroll
                    for (int r = 0; r < 16; r++) { o0[r] *= alpha; o1[r] *= alpha; }
                }

                // ---- P = 2^(s*c2 - m*c2)  (scale folded into one FMA) ----
                const float nem = -m_i * c2;
                float rs0 = 0.f, rs1 = 0.f;
#pragma unroll
                for (int r = 0; r < 16; r++) {
                    s0[r] = __builtin_amdgcn_exp2f(__builtin_fmaf(s0[r], c2, nem));
                    s1[r] = __builtin_amdgcn_exp2f(__builtin_fmaf(s1[r], c2, nem));
                    rs0 += s0[r]; rs1 += s1[r];
                }
                float rs = rs0 + rs1;
                rs += __shfl_xor(rs, 32);
                l_i += rs;

                // ---- pack P to bf16 words in-register (T12) ----
                unsigned u0[8], u1[8];
#pragma unroll
                for (int g = 0; g < 4; g++) {
                    u0[2 * g]     = cvtpk(s0[4 * g],     s0[4 * g + 1]);
                    u0[2 * g + 1] = cvtpk(s0[4 * g + 2], s0[4 * g + 3]);
                    u1[2 * g]     = cvtpk(s1[4 * g],     s1[4 * g + 1]);
                    u1[2 * g + 1] = cvtpk(s1[4 * g + 2], s1[4 * g + 3]);
                }
                unsigned pw[16];
#pragma unroll
                for (int t = 0; t < 2; t++) {
                    const unsigned* u = t ? u1 : u0;
#pragma unroll
                    for (int p = 0; p < 2; p++) {
#pragma unroll
                        for (int i = 0; i < 2; i++) {
                            uintx2 r = pl32(u[4 * p + i], u[4 * p + 2 + i]);
                            pw[8 * t + 4 * p + i]     = r[0];
                            pw[8 * t + 4 * p + 2 + i] = r[1];
                        }
                    }
                }

                // ---- O^T += V^T P^T ----
                __builtin_amdgcn_s_setprio(1);
#pragma unroll
                for (int ks = 0; ks < 4; ks++) {
                    int slot = ((hf + 2 * ks) ^ qs7) * 8;
                    short8 v0 = *(const short8*)&Vs[l31 * 64 + slot];
                    short8 v1 = *(const short8*)&Vs[(32 + l31) * 64 + slot];
                    short8 pf = mk8(pw[4 * ks], pw[4 * ks + 1], pw[4 * ks + 2], pw[4 * ks + 3]);
                    o0 = MFMA32(v0, pf, o0);
                    o1 = MFMA32(v1, pf, o1);
                }
                __builtin_amdgcn_s_setprio(0);
            }

            // ---- drain this tile's staging loads, then block-wide barrier ----
            asm volatile("s_waitcnt vmcnt(0)" ::: "memory");
            __builtin_amdgcn_s_barrier();
            cur ^= 1;
        }

        // ---- epilogue: /l, transpose via per-wave chunk of the (dead) K/V LDS ----
        ushort_t* Ew = SM + wv * 2048;          // 32x64 bf16 per wave
        float inv = 1.0f / l_i;
#pragma unroll
        for (int g = 0; g < 4; g++) {
            uint2 w0, w1;
            w0.x = cvtpk(o0[g * 4] * inv,     o0[g * 4 + 1] * inv);
            w0.y = cvtpk(o0[g * 4 + 2] * inv, o0[g * 4 + 3] * inv);
            w1.x = cvtpk(o1[g * 4] * inv,     o1[g * 4 + 1] * inv);
            w1.y = cvtpk(o1[g * 4 + 2] * inv, o1[g * 4 + 3] * inv);
            *(uint2*)&Ew[l31 * 64 + ((g       ^ qs7) * 8) + 4 * hf] = w0;   // d 8g+4hf+{0..3}
            *(uint2*)&Ew[l31 * 64 + (((4 + g) ^ qs7) * 8) + 4 * hf] = w1;   // d+32
        }
        const int dg = lane & 7;
#pragma unroll
        for (int sb = 0; sb < 4; sb++) {
            int ql = sb * 8 + (lane >> 3);
            uint4 v = *(const uint4*)&Ew[ql * 64 + ((dg ^ (ql & 7)) * 8)];
            *(uint4*)&Y[((size_t)(b * SEQ + qrow0 + ql)) * EMB + hh * HDIM + dg * 8] = v;
        }
        __syncthreads();   // protect Ew region before next pass re-stages over it
    }
}

// ---------------- launch ----------------
extern "C" void kernel_launch(void* const* d_in, const int* in_sizes, int n_in,
                              void* d_out, int out_size, void* d_ws, size_t ws_size,
                              hipStream_t stream) {
    const float* x      = (const float*)d_in[0];   // [8192][1024] fp32
    const float* W_attn = (const float*)d_in[1];   // [1024][3072] fp32
    const float* W_proj = (const float*)d_in[2];   // [1024][1024] fp32

    char* ws = (char*)d_ws;
    ushort_t* Wt_attn = (ushort_t*)(ws);                 // [3072][1024] bf16  6.3 MB
    ushort_t* Wt_proj = (ushort_t*)(ws + 6291456);       // [1024][1024] bf16  2.1 MB
    ushort_t* Xb      = (ushort_t*)(ws + 8388608);       // [8192][1024] bf16 16.8 MB
    ushort_t* Vt      = Xb;                              // alias: Xb dead after QKV gemm
    ushort_t* Qb      = (ushort_t*)(ws + 25165824);      // [64][2048][64]
    ushort_t* Kb      = (ushort_t*)(ws + 41943040);      // [64][2048][64]
    ushort_t* Vb      = (ushort_t*)(ws + 58720256);      // [64][2048][64]
    ushort_t* Yb      = Vb;                              // alias: Vb dead after transpose_v
    // total ws use: 75,497,472 B

    cast_k<<<4096, 256, 0, stream>>>(x, Xb);
    transpose_cast_k<<<dim3(3072 / 32, 1024 / 32), dim3(32, 8), 0, stream>>>(W_attn, Wt_attn, 1024, 3072);
    transpose_cast_k<<<dim3(1024 / 32, 1024 / 32), dim3(32, 8), 0, stream>>>(W_proj, Wt_proj, 1024, 1024);
    gemm_bt<1><<<dim3(8192 / 128, 3072 / 128), 256, 0, stream>>>(Xb, Wt_attn, Qb, Kb, Vb, 8192, 3072, 1024);
    transpose_v_k<<<dim3(SEQ / 32, HDIM / 32, 64), dim3(32, 8), 0, stream>>>(Vb, Vt);
    attn3_k<<<dim3(8, 64), 256, 0, stream>>>(Qb, Kb, Vt, Yb);
    gemm_bt<0><<<dim3(8192 / 128, 1024 / 128), 256, 0, stream>>>(Yb, Wt_proj, d_out,
                                                                 nullptr, nullptr, 8192, 1024, 1024);
}